// Round 1
// baseline (466.753 us; speedup 1.0000x reference)
//
#include <hip/hip_runtime.h>
#include <math.h>

// MS-SSIM loss, 5 levels, 11-tap separable Gaussian (sigma=1.5), VALID padding.
// Inputs: X, Y float32 (32,3,512,512) -> 96 channel-images of SxS.
// Per level: fused kernel computes ssim/cs spatial sums per (n,c) AND writes the
// 2x2 avg-pooled next-level images from the staged LDS tile.

#define TILE 32
#define TIN  42   // TILE + 10 (halo for 11-tap valid conv)
#define SROW 44   // padded LDS row stride

struct GWin { float w[11]; };

__global__ __launch_bounds__(256)
void ssim_level_kernel(const float* __restrict__ X, const float* __restrict__ Y,
                       float* __restrict__ poolX, float* __restrict__ poolY,
                       float* __restrict__ accum,   // [0..95]=ssim sums, [96..191]=cs sums
                       int S, int outS, int doPool, GWin gw)
{
    __shared__ float sx[TIN][SROW];
    __shared__ float sy[TIN][SROW];
    __shared__ float hb[5][TIN][TILE];
    __shared__ float rs[4], rc[4];

    const int ch  = blockIdx.z;      // 0..95 (n*c)
    const int gx0 = blockIdx.x * TILE;
    const int gy0 = blockIdx.y * TILE;
    const int tid = threadIdx.x;

    const float* Xc = X + (size_t)ch * S * S;
    const float* Yc = Y + (size_t)ch * S * S;

    // ---- stage 42x42 input region (zero-padded at image edge; unused there) ----
    for (int i = tid; i < TIN * TIN; i += 256) {
        int r = i / TIN, c = i % TIN;
        int gr = gy0 + r, gc = gx0 + c;
        float xv = 0.f, yv = 0.f;
        if (gr < S && gc < S) {
            size_t idx = (size_t)gr * S + gc;
            xv = Xc[idx];
            yv = Yc[idx];
        }
        sx[r][c] = xv;
        sy[r][c] = yv;
    }
    __syncthreads();

    // ---- horizontal 11-tap pass on 5 moment maps ----
    for (int i = tid; i < TIN * TILE; i += 256) {
        int r = i / TILE, c = i % TILE;
        float a0 = 0.f, a1 = 0.f, a2 = 0.f, a3 = 0.f, a4 = 0.f;
        #pragma unroll
        for (int k = 0; k < 11; ++k) {
            float w  = gw.w[k];
            float xv = sx[r][c + k];
            float yv = sy[r][c + k];
            a0 += w * xv;
            a1 += w * yv;
            a2 += w * xv * xv;
            a3 += w * yv * yv;
            a4 += w * xv * yv;
        }
        hb[0][r][c] = a0; hb[1][r][c] = a1; hb[2][r][c] = a2;
        hb[3][r][c] = a3; hb[4][r][c] = a4;
    }
    __syncthreads();

    // ---- vertical 11-tap pass + SSIM math + per-thread accumulate ----
    const float C1 = 1e-4f, C2 = 9e-4f;
    float ssum = 0.f, csum = 0.f;
    for (int i = tid; i < TILE * TILE; i += 256) {
        int r = i / TILE, c = i % TILE;
        int oy = gy0 + r, ox = gx0 + c;
        if (oy < outS && ox < outS) {
            float m1 = 0.f, m2 = 0.f, e11 = 0.f, e22 = 0.f, e12 = 0.f;
            #pragma unroll
            for (int k = 0; k < 11; ++k) {
                float w = gw.w[k];
                m1  += w * hb[0][r + k][c];
                m2  += w * hb[1][r + k][c];
                e11 += w * hb[2][r + k][c];
                e22 += w * hb[3][r + k][c];
                e12 += w * hb[4][r + k][c];
            }
            float mu12 = m1 * m2;
            float s11  = e11 - m1 * m1;
            float s22  = e22 - m2 * m2;
            float s12  = e12 - mu12;
            float cs   = (2.f * s12 + C2) / (s11 + s22 + C2);
            float ss   = ((2.f * mu12 + C1) / (m1 * m1 + m2 * m2 + C1)) * cs;
            ssum += ss;
            csum += cs;
        }
    }

    // ---- 2x2 avg-pool of owned 32x32 region into next level (from LDS) ----
    if (doPool) {
        int pr = tid / 16, pc = tid % 16;      // 16x16 pooled outputs per block
        int halfS = S >> 1;
        int py = (gy0 >> 1) + pr, px = (gx0 >> 1) + pc;
        if (py < halfS && px < halfS) {
            int r = 2 * pr, c = 2 * pc;
            float xa = 0.25f * (sx[r][c] + sx[r][c + 1] + sx[r + 1][c] + sx[r + 1][c + 1]);
            float ya = 0.25f * (sy[r][c] + sy[r][c + 1] + sy[r + 1][c] + sy[r + 1][c + 1]);
            size_t o = (size_t)ch * halfS * halfS + (size_t)py * halfS + px;
            poolX[o] = xa;
            poolY[o] = ya;
        }
    }

    // ---- block reduction + atomic accumulate ----
    for (int off = 32; off > 0; off >>= 1) {
        ssum += __shfl_down(ssum, off);
        csum += __shfl_down(csum, off);
    }
    int wid = tid >> 6, lane = tid & 63;
    if (lane == 0) { rs[wid] = ssum; rc[wid] = csum; }
    __syncthreads();
    if (tid == 0) {
        float s = rs[0] + rs[1] + rs[2] + rs[3];
        float c = rc[0] + rc[1] + rc[2] + rc[3];
        atomicAdd(&accum[ch], s);
        atomicAdd(&accum[96 + ch], c);
    }
}

__global__ void finalize_kernel(const float* __restrict__ accum, float* __restrict__ out)
{
    __shared__ float red[2];
    const int t = threadIdx.x;   // 128 threads
    const float w[5]   = {0.0448f, 0.2856f, 0.3001f, 0.2363f, 0.1333f};
    const float inv[5] = {1.f / (502.f * 502.f), 1.f / (246.f * 246.f),
                          1.f / (118.f * 118.f), 1.f / (54.f * 54.f),
                          1.f / (22.f * 22.f)};
    float ms = 0.f;
    if (t < 96) {
        ms = 1.f;
        #pragma unroll
        for (int l = 0; l < 5; ++l) {
            float v = (l < 4) ? accum[l * 192 + 96 + t] : accum[l * 192 + t];
            v *= inv[l];
            v = fmaxf(v, 0.f);
            ms *= powf(v, w[l]);
        }
    }
    for (int off = 32; off > 0; off >>= 1) ms += __shfl_down(ms, off);
    int wid = t >> 6, lane = t & 63;
    if (lane == 0) red[wid] = ms;
    __syncthreads();
    if (t == 0) out[0] = 1.f - (red[0] + red[1]) * (1.f / 96.f);
}

extern "C" void kernel_launch(void* const* d_in, const int* in_sizes, int n_in,
                              void* d_out, int out_size, void* d_ws, size_t ws_size,
                              hipStream_t stream)
{
    (void)in_sizes; (void)n_in; (void)out_size; (void)ws_size;
    const float* X = (const float*)d_in[0];
    const float* Y = (const float*)d_in[1];
    float* out = (float*)d_out;
    float* ws  = (float*)d_ws;

    // Gaussian window (size 11, sigma 1.5), normalized
    GWin gw;
    {
        double g[11], s = 0.0;
        for (int i = 0; i < 11; ++i) { double d = i - 5; g[i] = exp(-(d * d) / 4.5); s += g[i]; }
        for (int i = 0; i < 11; ++i) gw.w[i] = (float)(g[i] / s);
    }

    // workspace layout (floats)
    float* accum = ws;                 // 5 levels * 192
    size_t off = 1024;
    float* p1x = ws + off; off += (size_t)96 * 256 * 256;
    float* p1y = ws + off; off += (size_t)96 * 256 * 256;
    float* p2x = ws + off; off += (size_t)96 * 128 * 128;
    float* p2y = ws + off; off += (size_t)96 * 128 * 128;
    float* p3x = ws + off; off += (size_t)96 * 64 * 64;
    float* p3y = ws + off; off += (size_t)96 * 64 * 64;
    float* p4x = ws + off; off += (size_t)96 * 32 * 32;
    float* p4y = ws + off; off += (size_t)96 * 32 * 32;

    hipMemsetAsync(accum, 0, 5 * 192 * sizeof(float), stream);

    // level grids: tiles = ceil((S-10)/32); note tiles*32 == S at every level,
    // so the fused pooling exactly covers the next level.
    ssim_level_kernel<<<dim3(16, 16, 96), 256, 0, stream>>>(X,   Y,   p1x, p1y, accum + 0,   512, 502, 1, gw);
    ssim_level_kernel<<<dim3(8,  8,  96), 256, 0, stream>>>(p1x, p1y, p2x, p2y, accum + 192, 256, 246, 1, gw);
    ssim_level_kernel<<<dim3(4,  4,  96), 256, 0, stream>>>(p2x, p2y, p3x, p3y, accum + 384, 128, 118, 1, gw);
    ssim_level_kernel<<<dim3(2,  2,  96), 256, 0, stream>>>(p3x, p3y, p4x, p4y, accum + 576, 64,  54,  1, gw);
    ssim_level_kernel<<<dim3(1,  1,  96), 256, 0, stream>>>(p4x, p4y, nullptr, nullptr, accum + 768, 32, 22, 0, gw);

    finalize_kernel<<<1, 128, 0, stream>>>(accum, out);
}

// Round 2
// 406.218 us; speedup vs baseline: 1.1490x; 1.1490x over previous
//
#include <hip/hip_runtime.h>
#include <math.h>

// MS-SSIM loss, 5 levels, 11-tap separable Gaussian (sigma=1.5), VALID padding.
// Optimized round 2: vectorized LDS traffic + register-tiled conv passes.

#define TILE 32
#define TIN  42   // TILE + 10 (halo for 11-tap valid conv)
#define SROW 44   // padded LDS row stride (16B-aligned rows: 44*4=176)

struct GWin { float w[11]; };

__global__ __launch_bounds__(256)
void ssim_level_kernel(const float* __restrict__ X, const float* __restrict__ Y,
                       float* __restrict__ poolX, float* __restrict__ poolY,
                       float* __restrict__ accum,   // [0..95]=ssim sums, [96..191]=cs sums
                       int S, int outS, int doPool, GWin gw)
{
    __shared__ float sx[TIN][SROW];
    __shared__ float sy[TIN][SROW];
    __shared__ float hb[5 * TIN * TILE];   // hb[m][r][c] = hb[m*1344 + r*32 + c]
    __shared__ float rs[4], rc[4];

    const int ch  = blockIdx.z;      // 0..95 (n*c)
    const int gx0 = blockIdx.x * TILE;
    const int gy0 = blockIdx.y * TILE;
    const int tid = threadIdx.x;

    const float* Xc = X + (size_t)ch * S * S;
    const float* Yc = Y + (size_t)ch * S * S;

    // ---- stage 42x42 input region (zero-padded past image edge) ----
    {
        int r0s = tid / 42;          // one div/mod total
        int cs  = tid % 42;
        if (tid < 252) {
            #pragma unroll
            for (int it = 0; it < 7; ++it) {
                int r  = r0s + it * 6;
                int gr = gy0 + r, gc = gx0 + cs;
                float xv = 0.f, yv = 0.f;
                if (gr < S && gc < S) {
                    size_t idx = (size_t)gr * S + gc;
                    xv = Xc[idx];
                    yv = Yc[idx];
                }
                sx[r][cs] = xv;
                sy[r][cs] = yv;
            }
        }
    }
    __syncthreads();

    // ---- 2x2 avg-pool into next level (global-store latency hides under h-pass) ----
    if (doPool) {
        int pr = tid >> 4, pc = tid & 15;      // 16x16 pooled outputs per block
        int halfS = S >> 1;
        int py = (gy0 >> 1) + pr, px = (gx0 >> 1) + pc;
        int r = 2 * pr, c = 2 * pc;
        float xa = 0.25f * (sx[r][c] + sx[r][c + 1] + sx[r + 1][c] + sx[r + 1][c + 1]);
        float ya = 0.25f * (sy[r][c] + sy[r][c + 1] + sy[r + 1][c] + sy[r + 1][c + 1]);
        size_t o = (size_t)ch * halfS * halfS + (size_t)py * halfS + px;
        poolX[o] = xa;
        poolY[o] = ya;
    }

    // ---- horizontal 11-tap pass, 4-wide output groups, vector LDS I/O ----
    // 42 rows * 8 groups = 336 groups of 4 outputs
    for (int g = tid; g < TIN * 8; g += 256) {
        int r  = g >> 3;
        int c4 = (g & 7) * 4;
        float4 x0 = *reinterpret_cast<const float4*>(&sx[r][c4]);
        float4 x1 = *reinterpret_cast<const float4*>(&sx[r][c4 + 4]);
        float4 x2 = *reinterpret_cast<const float4*>(&sx[r][c4 + 8]);
        float4 x3 = *reinterpret_cast<const float4*>(&sx[r][c4 + 12]);
        float4 y0 = *reinterpret_cast<const float4*>(&sy[r][c4]);
        float4 y1 = *reinterpret_cast<const float4*>(&sy[r][c4 + 4]);
        float4 y2 = *reinterpret_cast<const float4*>(&sy[r][c4 + 8]);
        float4 y3 = *reinterpret_cast<const float4*>(&sy[r][c4 + 12]);
        float xv[14], yv[14];
        xv[0]=x0.x; xv[1]=x0.y; xv[2]=x0.z; xv[3]=x0.w;
        xv[4]=x1.x; xv[5]=x1.y; xv[6]=x1.z; xv[7]=x1.w;
        xv[8]=x2.x; xv[9]=x2.y; xv[10]=x2.z; xv[11]=x2.w;
        xv[12]=x3.x; xv[13]=x3.y;
        yv[0]=y0.x; yv[1]=y0.y; yv[2]=y0.z; yv[3]=y0.w;
        yv[4]=y1.x; yv[5]=y1.y; yv[6]=y1.z; yv[7]=y1.w;
        yv[8]=y2.x; yv[9]=y2.y; yv[10]=y2.z; yv[11]=y2.w;
        yv[12]=y3.x; yv[13]=y3.y;
        float xx[14], yy[14], xy[14];
        #pragma unroll
        for (int i = 0; i < 14; ++i) {
            xx[i] = xv[i] * xv[i];
            yy[i] = yv[i] * yv[i];
            xy[i] = xv[i] * yv[i];
        }
        float a[5][4];
        #pragma unroll
        for (int m = 0; m < 5; ++m)
            #pragma unroll
            for (int j = 0; j < 4; ++j) a[m][j] = 0.f;
        #pragma unroll
        for (int j = 0; j < 4; ++j) {
            #pragma unroll
            for (int k = 0; k < 11; ++k) {
                float w = gw.w[k];
                a[0][j] += w * xv[j + k];
                a[1][j] += w * yv[j + k];
                a[2][j] += w * xx[j + k];
                a[3][j] += w * yy[j + k];
                a[4][j] += w * xy[j + k];
            }
        }
        #pragma unroll
        for (int m = 0; m < 5; ++m) {
            *reinterpret_cast<float4*>(&hb[m * (TIN * TILE) + r * TILE + c4]) =
                make_float4(a[m][0], a[m][1], a[m][2], a[m][3]);
        }
    }
    __syncthreads();

    // ---- vertical 11-tap pass: 1x4 vertical output group per thread ----
    const float C1 = 1e-4f, C2 = 9e-4f;
    float ssum = 0.f, csum = 0.f;
    {
        int c  = tid & 31;
        int r0 = (tid >> 5) * 4;            // 8 strips * 4 rows = 32
        float acc[5][4];
        #pragma unroll
        for (int m = 0; m < 5; ++m)
            #pragma unroll
            for (int j = 0; j < 4; ++j) acc[m][j] = 0.f;
        const float* hbp = &hb[r0 * TILE + c];
        #pragma unroll
        for (int m = 0; m < 5; ++m) {
            #pragma unroll
            for (int k = 0; k < 14; ++k) {
                float v = hbp[m * (TIN * TILE) + k * TILE];
                #pragma unroll
                for (int j = 0; j < 4; ++j) {
                    if (j <= k && k - j <= 10)
                        acc[m][j] += gw.w[k - j] * v;
                }
            }
        }
        int ox = gx0 + c;
        #pragma unroll
        for (int j = 0; j < 4; ++j) {
            int oy = gy0 + r0 + j;
            if (oy < outS && ox < outS) {
                float m1  = acc[0][j], m2 = acc[1][j];
                float e11 = acc[2][j], e22 = acc[3][j], e12 = acc[4][j];
                float mu12 = m1 * m2;
                float m1sq = m1 * m1, m2sq = m2 * m2;
                float s11  = e11 - m1sq;
                float s22  = e22 - m2sq;
                float s12  = e12 - mu12;
                float cs = (2.f * s12 + C2) * __builtin_amdgcn_rcpf(s11 + s22 + C2);
                float ss = (2.f * mu12 + C1) * __builtin_amdgcn_rcpf(m1sq + m2sq + C1) * cs;
                ssum += ss;
                csum += cs;
            }
        }
    }

    // ---- block reduction + atomic accumulate ----
    for (int off = 32; off > 0; off >>= 1) {
        ssum += __shfl_down(ssum, off);
        csum += __shfl_down(csum, off);
    }
    int wid = tid >> 6, lane = tid & 63;
    if (lane == 0) { rs[wid] = ssum; rc[wid] = csum; }
    __syncthreads();
    if (tid == 0) {
        float s = rs[0] + rs[1] + rs[2] + rs[3];
        float c = rc[0] + rc[1] + rc[2] + rc[3];
        atomicAdd(&accum[ch], s);
        atomicAdd(&accum[96 + ch], c);
    }
}

__global__ void finalize_kernel(const float* __restrict__ accum, float* __restrict__ out)
{
    __shared__ float red[2];
    const int t = threadIdx.x;   // 128 threads
    const float w[5]   = {0.0448f, 0.2856f, 0.3001f, 0.2363f, 0.1333f};
    const float inv[5] = {1.f / (502.f * 502.f), 1.f / (246.f * 246.f),
                          1.f / (118.f * 118.f), 1.f / (54.f * 54.f),
                          1.f / (22.f * 22.f)};
    float ms = 0.f;
    if (t < 96) {
        ms = 1.f;
        #pragma unroll
        for (int l = 0; l < 5; ++l) {
            float v = (l < 4) ? accum[l * 192 + 96 + t] : accum[l * 192 + t];
            v *= inv[l];
            v = fmaxf(v, 0.f);
            ms *= powf(v, w[l]);
        }
    }
    for (int off = 32; off > 0; off >>= 1) ms += __shfl_down(ms, off);
    int wid = t >> 6, lane = t & 63;
    if (lane == 0) red[wid] = ms;
    __syncthreads();
    if (t == 0) out[0] = 1.f - (red[0] + red[1]) * (1.f / 96.f);
}

extern "C" void kernel_launch(void* const* d_in, const int* in_sizes, int n_in,
                              void* d_out, int out_size, void* d_ws, size_t ws_size,
                              hipStream_t stream)
{
    (void)in_sizes; (void)n_in; (void)out_size; (void)ws_size;
    const float* X = (const float*)d_in[0];
    const float* Y = (const float*)d_in[1];
    float* out = (float*)d_out;
    float* ws  = (float*)d_ws;

    // Gaussian window (size 11, sigma 1.5), normalized
    GWin gw;
    {
        double g[11], s = 0.0;
        for (int i = 0; i < 11; ++i) { double d = i - 5; g[i] = exp(-(d * d) / 4.5); s += g[i]; }
        for (int i = 0; i < 11; ++i) gw.w[i] = (float)(g[i] / s);
    }

    // workspace layout (floats)
    float* accum = ws;                 // 5 levels * 192
    size_t off = 1024;
    float* p1x = ws + off; off += (size_t)96 * 256 * 256;
    float* p1y = ws + off; off += (size_t)96 * 256 * 256;
    float* p2x = ws + off; off += (size_t)96 * 128 * 128;
    float* p2y = ws + off; off += (size_t)96 * 128 * 128;
    float* p3x = ws + off; off += (size_t)96 * 64 * 64;
    float* p3y = ws + off; off += (size_t)96 * 64 * 64;
    float* p4x = ws + off; off += (size_t)96 * 32 * 32;
    float* p4y = ws + off; off += (size_t)96 * 32 * 32;

    hipMemsetAsync(accum, 0, 5 * 192 * sizeof(float), stream);

    // level grids: tiles*32 == S at every level, so fused pooling exactly
    // covers the next level.
    ssim_level_kernel<<<dim3(16, 16, 96), 256, 0, stream>>>(X,   Y,   p1x, p1y, accum + 0,   512, 502, 1, gw);
    ssim_level_kernel<<<dim3(8,  8,  96), 256, 0, stream>>>(p1x, p1y, p2x, p2y, accum + 192, 256, 246, 1, gw);
    ssim_level_kernel<<<dim3(4,  4,  96), 256, 0, stream>>>(p2x, p2y, p3x, p3y, accum + 384, 128, 118, 1, gw);
    ssim_level_kernel<<<dim3(2,  2,  96), 256, 0, stream>>>(p3x, p3y, p4x, p4y, accum + 576, 64,  54,  1, gw);
    ssim_level_kernel<<<dim3(1,  1,  96), 256, 0, stream>>>(p4x, p4y, nullptr, nullptr, accum + 768, 32, 22, 0, gw);

    finalize_kernel<<<1, 128, 0, stream>>>(accum, out);
}